// Round 1
// baseline (139.405 us; speedup 1.0000x reference)
//
#include <hip/hip_runtime.h>
#include <cstdint>
#include <cstddef>

#define VOCAB 50000
#define EMBED 256
#define BATCH 16384
#define NSAMP 4096

typedef float f32x4 __attribute__((ext_vector_type(4)));
typedef int   i32x8 __attribute__((ext_vector_type(8)));

// ---------- helpers ----------

__device__ __forceinline__ f32x4 vsplat(float a) {
    f32x4 r = {a, a, a, a};
    return r;
}

// Pure-HW log(expected_count): no libm calls (validated r6-r8, absmax 0.0).
__device__ __forceinline__ float log_expected_count(int id) {
    float u = 1.0f / ((float)id + 1.0f);
    float a = __logf(1.0f + u);
    float p = a * 0.09242324f;   // 1/log(50001)
    float ser = p * (1.0f + p * (0.5f + p * (0.33333333f + p * (0.25f + p * 0.2f))));
    float q = -(float)NSAMP * ser;
    return __logf(1.0f - __expf(q));
}

// softplus(x) = max(x,0) + log1p(e^{-|x|}); deg-5 minimax (|err|<=1e-5)
__device__ __forceinline__ float softplus_f(float x) {
    float v = __expf(-fabsf(x));
    float p = fmaf(v, 0.03215845f, -0.13606275f);
    p = fmaf(v, p, 0.28947478f);
    p = fmaf(v, p, -0.49190896f);
    p = fmaf(v, p, 0.99949556f);
    return fmaxf(x, 0.0f) + v * p;
}

// Packed-f32 softplus over 4 lanes-elements: same minimax poly, but the
// poly/max/add run as v_pk_* (full-rate packed fp32 on gfx950) and the
// accumulator is a 4-wide chain instead of one serial float chain.
__device__ __forceinline__ void softplus4_acc(f32x4 x, f32x4& vsum) {
    f32x4 ax = __builtin_elementwise_abs(x);
    f32x4 v;
    v.x = __expf(-ax.x);
    v.y = __expf(-ax.y);
    v.z = __expf(-ax.z);
    v.w = __expf(-ax.w);
    f32x4 p = __builtin_elementwise_fma(v, vsplat(0.03215845f), vsplat(-0.13606275f));
    p = __builtin_elementwise_fma(v, p, vsplat(0.28947478f));
    p = __builtin_elementwise_fma(v, p, vsplat(-0.49190896f));
    p = __builtin_elementwise_fma(v, p, vsplat(0.99949556f));
    vsum += __builtin_elementwise_max(x, vsplat(0.0f));
    vsum = __builtin_elementwise_fma(v, p, vsum);
}

// pack 4 floats -> 4 fp8 e4m3 bytes (HW cvt, OCP on gfx950)
__device__ __forceinline__ int pk4_fp8(float a, float b, float c, float d) {
    int v = __builtin_amdgcn_cvt_pk_fp8_f32(a, b, 0, false);
    v = __builtin_amdgcn_cvt_pk_fp8_f32(c, d, v, true);
    return v;
}

// Fragment-order layout for an R x 256 fp8 matrix:
//   offset(r,k) = (r>>4)*4096 + (k>>5)*512 + (r&15)*32 + (k&31)
// Wave frag (group g, k-step s): contiguous 2KB at g*4096 + s*2048,
// per-lane 32B at +lane*32 (lane&15 = row, lane>>4 = k-quad).

// ---------- kernels ----------

// blocks [0,1024): true logits + E -> fp8 fragments (1 wave = 4 rows)
// blocks [1024,1088): gather W[sids] * 16 -> fp8 fragments + badj
__global__ __launch_bounds__(256) void k_prep(
        const float* __restrict__ E, const int* __restrict__ tgt,
        const int* __restrict__ sids, const float* __restrict__ W,
        const float* __restrict__ bias,
        unsigned char* __restrict__ EF, unsigned char* __restrict__ BF,
        float* __restrict__ badj, double* __restrict__ pTrue)
{
    const int blk = blockIdx.x, tid = threadIdx.x;
    const int wave = tid >> 6, lane = tid & 63;

    if (blk < 1024) {
        float tsum = 0.0f;
        #pragma unroll
        for (int i = 0; i < 4; ++i) {
            int b = (blk * 4 + wave) + 4096 * i;
            int label = tgt[b];
            float4 e  = ((const float4*)(E + (size_t)b * EMBED))[lane];
            float4 wv = ((const float4*)(W + (size_t)label * EMBED))[lane];
            int pk = pk4_fp8(e.x, e.y, e.z, e.w);
            *(int*)(EF + ((b >> 4) * 4096 + (lane >> 3) * 512
                          + (b & 15) * 32 + (lane & 7) * 4)) = pk;
            float d = e.x * wv.x + e.y * wv.y + e.z * wv.z + e.w * wv.w;
            #pragma unroll
            for (int off = 32; off > 0; off >>= 1) d += __shfl_down(d, off, 64);
            if (lane == 0) {
                float tl = d + bias[label] - log_expected_count(label);
                tsum += softplus_f(-tl);
            }
        }
        __shared__ float ts[4];
        if (lane == 0) ts[wave] = tsum;
        __syncthreads();
        if (tid == 0) pTrue[blk] = (double)((ts[0] + ts[1]) + (ts[2] + ts[3]));
    } else {
        #pragma unroll
        for (int i = 0; i < 4; ++i) {
            int task = (blk - 1024) * 256 + tid + 16384 * i;
            int s = task >> 4, p = task & 15;   // p = 16B chunk, k = p*16
            int sid = sids[s];
            const float4* wr = (const float4*)(W + (size_t)sid * EMBED + p * 16);
            float4 w0 = wr[0], w1 = wr[1], w2 = wr[2], w3 = wr[3];
            int4 o;
            o.x = pk4_fp8(w0.x * 16.0f, w0.y * 16.0f, w0.z * 16.0f, w0.w * 16.0f);
            o.y = pk4_fp8(w1.x * 16.0f, w1.y * 16.0f, w1.z * 16.0f, w1.w * 16.0f);
            o.z = pk4_fp8(w2.x * 16.0f, w2.y * 16.0f, w2.z * 16.0f, w2.w * 16.0f);
            o.w = pk4_fp8(w3.x * 16.0f, w3.y * 16.0f, w3.z * 16.0f, w3.w * 16.0f);
            *(int4*)(BF + ((s >> 4) * 4096 + (p >> 1) * 512
                           + (s & 15) * 32 + (p & 1) * 16)) = o;
            if (p == 0) badj[s] = bias[sid] - log_expected_count(sid);
        }
    }
}

// GEMM: direct-register MX-fp8, no LDS (r8 inner structure, spill-free).
// Grid 1024: blk>>4 = 256-row group, blk&15 = 256-col group -> 4 blocks/CU
// available (r8's 512 grid capped the machine at 2 waves/SIMD; counters showed
// MfmaUtil 16 + VALUBusy 47 + Occupancy 19 = starved for waves, not work).
// Quarter-split accumulators keep peak regs ~(256,3)-compatible.
// Epilogue: packed-f32 softplus (v_pk_fma/pk_max/pk_add) with a 4-wide
// accumulator chain instead of the serial scalar lsum chain.
__global__ __launch_bounds__(256, 3) void k_gemm(
        const unsigned char* __restrict__ EF,
        const unsigned char* __restrict__ BF,
        const float* __restrict__ badj,
        double* __restrict__ pGemm)
{
    const int tid  = threadIdx.x;
    const int wave = tid >> 6;
    const int lane = tid & 63;
    const int rg   = blockIdx.x >> 4;     // 256-row group (0..63)
    const int cg   = blockIdx.x & 15;     // 256-col group (0..15)
    const int ag0  = rg * 16 + wave * 4;  // A 16-row group base
    const int r16  = lane & 15;

    i32x8 af[2][4];
    #pragma unroll
    for (int s = 0; s < 2; ++s)
        #pragma unroll
        for (int mi = 0; mi < 4; ++mi)
            af[s][mi] = *(const i32x8*)(EF + (size_t)(ag0 + mi) * 4096
                                        + s * 2048 + lane * 32);

    f32x4 vsum = {};

    #pragma unroll 1
    for (int j = 0; j < 4; ++j) {
        const int bg0 = cg * 16 + j * 4;          // B 16-row group base
        i32x8 bf[2][4];
        #pragma unroll
        for (int s = 0; s < 2; ++s)
            #pragma unroll
            for (int ni = 0; ni < 4; ++ni)
                bf[s][ni] = *(const i32x8*)(BF + (size_t)(bg0 + ni) * 4096
                                            + s * 2048 + lane * 32);

        float ba[4];
        #pragma unroll
        for (int ni = 0; ni < 4; ++ni)
            ba[ni] = badj[cg * 256 + j * 64 + ni * 16 + r16];

        #pragma unroll
        for (int mi = 0; mi < 4; ++mi) {
            f32x4 acc[4] = {};
            #pragma unroll
            for (int s = 0; s < 2; ++s)
                #pragma unroll
                for (int ni = 0; ni < 4; ++ni)
                    acc[ni] = __builtin_amdgcn_mfma_scale_f32_16x16x128_f8f6f4(
                        af[s][mi], bf[s][ni], acc[ni],
                        0, 0,                 // cbsz=fp8, blgp=fp8
                        0, 0x7F7F7F7F,        // scale A = 2^0
                        0, 0x7B7B7B7B);       // scale B = 2^-4 (undo W*16)
            #pragma unroll
            for (int ni = 0; ni < 4; ++ni)
                softplus4_acc(acc[ni] + ba[ni], vsum);
        }
    }

    float lsum = (vsum.x + vsum.y) + (vsum.z + vsum.w);
    #pragma unroll
    for (int off = 32; off > 0; off >>= 1) lsum += __shfl_down(lsum, off, 64);
    __shared__ float wsum[4];
    if (lane == 0) wsum[wave] = lsum;
    __syncthreads();
    if (tid == 0)
        pGemm[blockIdx.x] = (double)((wsum[0] + wsum[1]) + (wsum[2] + wsum[3]));
}

__global__ __launch_bounds__(256) void k_final(
        const double* __restrict__ pTrue, const double* __restrict__ pGemm,
        float* __restrict__ out)
{
    const int tid = threadIdx.x, wave = tid >> 6, lane = tid & 63;
    double s = 0.0;
    for (int i = tid; i < 1024; i += 256) s += pTrue[i];
    for (int i = tid; i < 1024; i += 256) s += pGemm[i];
    #pragma unroll
    for (int off = 32; off > 0; off >>= 1) s += __shfl_down(s, off, 64);
    __shared__ double wsum[4];
    if (lane == 0) wsum[wave] = s;
    __syncthreads();
    if (tid == 0)
        out[0] = (float)(((wsum[0] + wsum[1]) + (wsum[2] + wsum[3]))
                         * (1.0 / (double)BATCH));
}

// ---------- launch ----------

extern "C" void kernel_launch(void* const* d_in, const int* in_sizes, int n_in,
                              void* d_out, int out_size, void* d_ws, size_t ws_size,
                              hipStream_t stream) {
    const float* emb  = (const float*)d_in[0];
    const int*   tgt  = (const int*)d_in[1];
    const int*   sids = (const int*)d_in[2];
    const float* W    = (const float*)d_in[3];
    const float* bias = (const float*)d_in[4];
    float* out = (float*)d_out;

    char* ws = (char*)d_ws;
    double*        pTrue = (double*)ws;                        // 1024 doubles
    double*        pGemm = (double*)(ws + 8192);               // 1024 doubles
    float*         badj  = (float*)(ws + 40960);               // 16 KB
    unsigned char* BF    = (unsigned char*)(ws + 57344);       // 1 MB
    unsigned char* EF    = (unsigned char*)(ws + 57344 + 1048576); // 4 MB

    hipLaunchKernelGGL(k_prep, dim3(1088), dim3(256), 0, stream,
                       emb, tgt, sids, W, bias, EF, BF, badj, pTrue);
    hipLaunchKernelGGL(k_gemm, dim3(1024), dim3(256), 0, stream,
                       EF, BF, badj, pGemm);
    hipLaunchKernelGGL(k_final, dim3(1), dim3(256), 0, stream,
                       pTrue, pGemm, out);
}

// Round 2
// 132.713 us; speedup vs baseline: 1.0504x; 1.0504x over previous
//
#include <hip/hip_runtime.h>
#include <cstdint>
#include <cstddef>

#define VOCAB 50000
#define EMBED 256
#define BATCH 16384
#define NSAMP 4096

typedef float f32x4 __attribute__((ext_vector_type(4)));
typedef int   i32x8 __attribute__((ext_vector_type(8)));

// ---------- helpers ----------

__device__ __forceinline__ f32x4 vsplat(float a) {
    f32x4 r = {a, a, a, a};
    return r;
}

// Pure-HW log(expected_count): no libm calls (validated r6-r8, absmax 0.0).
__device__ __forceinline__ float log_expected_count(int id) {
    float u = 1.0f / ((float)id + 1.0f);
    float a = __logf(1.0f + u);
    float p = a * 0.09242324f;   // 1/log(50001)
    float ser = p * (1.0f + p * (0.5f + p * (0.33333333f + p * (0.25f + p * 0.2f))));
    float q = -(float)NSAMP * ser;
    return __logf(1.0f - __expf(q));
}

// softplus(x) = max(x,0) + log1p(e^{-|x|}); deg-5 minimax (|err|<=1e-5)
__device__ __forceinline__ float softplus_f(float x) {
    float v = __expf(-fabsf(x));
    float p = fmaf(v, 0.03215845f, -0.13606275f);
    p = fmaf(v, p, 0.28947478f);
    p = fmaf(v, p, -0.49190896f);
    p = fmaf(v, p, 0.99949556f);
    return fmaxf(x, 0.0f) + v * p;
}

// Packed-f32 softplus over 4 elements (v_pk_* on gfx950), 4-wide acc chain.
__device__ __forceinline__ void softplus4_acc(f32x4 x, f32x4& vsum) {
    f32x4 ax = __builtin_elementwise_abs(x);
    f32x4 v;
    v.x = __expf(-ax.x);
    v.y = __expf(-ax.y);
    v.z = __expf(-ax.z);
    v.w = __expf(-ax.w);
    f32x4 p = __builtin_elementwise_fma(v, vsplat(0.03215845f), vsplat(-0.13606275f));
    p = __builtin_elementwise_fma(v, p, vsplat(0.28947478f));
    p = __builtin_elementwise_fma(v, p, vsplat(-0.49190896f));
    p = __builtin_elementwise_fma(v, p, vsplat(0.99949556f));
    vsum += __builtin_elementwise_max(x, vsplat(0.0f));
    vsum = __builtin_elementwise_fma(v, p, vsum);
}

// pack 4 floats -> 4 fp8 e4m3 bytes (HW cvt, OCP on gfx950)
__device__ __forceinline__ int pk4_fp8(float a, float b, float c, float d) {
    int v = __builtin_amdgcn_cvt_pk_fp8_f32(a, b, 0, false);
    v = __builtin_amdgcn_cvt_pk_fp8_f32(c, d, v, true);
    return v;
}

// Fragment-order layout for an R x 256 fp8 matrix:
//   offset(r,k) = (r>>4)*4096 + (k>>5)*512 + (r&15)*32 + (k&31)
// Wave frag (group g, k-step s): contiguous 2KB at g*4096 + s*2048,
// per-lane 32B at +lane*32 (lane&15 = row, lane>>4 = k-quad).

// ---------- kernels ----------

// blocks [0,1024): true logits + E -> fp8 fragments (1 wave = 4 rows)
// blocks [1024,1088): gather W[sids] * 16 -> fp8 fragments + badj
__global__ __launch_bounds__(256) void k_prep(
        const float* __restrict__ E, const int* __restrict__ tgt,
        const int* __restrict__ sids, const float* __restrict__ W,
        const float* __restrict__ bias,
        unsigned char* __restrict__ EF, unsigned char* __restrict__ BF,
        float* __restrict__ badj, double* __restrict__ pTrue)
{
    const int blk = blockIdx.x, tid = threadIdx.x;
    const int wave = tid >> 6, lane = tid & 63;

    if (blk < 1024) {
        float tsum = 0.0f;
        #pragma unroll
        for (int i = 0; i < 4; ++i) {
            int b = (blk * 4 + wave) + 4096 * i;
            int label = tgt[b];
            float4 e  = ((const float4*)(E + (size_t)b * EMBED))[lane];
            float4 wv = ((const float4*)(W + (size_t)label * EMBED))[lane];
            int pk = pk4_fp8(e.x, e.y, e.z, e.w);
            *(int*)(EF + ((b >> 4) * 4096 + (lane >> 3) * 512
                          + (b & 15) * 32 + (lane & 7) * 4)) = pk;
            float d = e.x * wv.x + e.y * wv.y + e.z * wv.z + e.w * wv.w;
            #pragma unroll
            for (int off = 32; off > 0; off >>= 1) d += __shfl_down(d, off, 64);
            if (lane == 0) {
                float tl = d + bias[label] - log_expected_count(label);
                tsum += softplus_f(-tl);
            }
        }
        __shared__ float ts[4];
        if (lane == 0) ts[wave] = tsum;
        __syncthreads();
        if (tid == 0) pTrue[blk] = (double)((ts[0] + ts[1]) + (ts[2] + ts[3]));
    } else {
        #pragma unroll
        for (int i = 0; i < 4; ++i) {
            int task = (blk - 1024) * 256 + tid + 16384 * i;
            int s = task >> 4, p = task & 15;   // p = 16B chunk, k = p*16
            int sid = sids[s];
            const float4* wr = (const float4*)(W + (size_t)sid * EMBED + p * 16);
            float4 w0 = wr[0], w1 = wr[1], w2 = wr[2], w3 = wr[3];
            int4 o;
            o.x = pk4_fp8(w0.x * 16.0f, w0.y * 16.0f, w0.z * 16.0f, w0.w * 16.0f);
            o.y = pk4_fp8(w1.x * 16.0f, w1.y * 16.0f, w1.z * 16.0f, w1.w * 16.0f);
            o.z = pk4_fp8(w2.x * 16.0f, w2.y * 16.0f, w2.z * 16.0f, w2.w * 16.0f);
            o.w = pk4_fp8(w3.x * 16.0f, w3.y * 16.0f, w3.z * 16.0f, w3.w * 16.0f);
            *(int4*)(BF + ((s >> 4) * 4096 + (p >> 1) * 512
                           + (s & 15) * 32 + (p & 1) * 16)) = o;
            if (p == 0) badj[s] = bias[sid] - log_expected_count(sid);
        }
    }
}

// GEMM: direct-register MX-fp8, no LDS.
// r1 counters: VGPR_Count=84 proved the compiler sank one 64-reg operand's
// loads into the loop (budget 170 @ (256,3)); FETCH 20MB (~4x ideal),
// MfmaUtil 13.5, latency-bound. Fix: (256,2) -> 256-reg budget; pin af in
// registers via "+v" asm redefinition; fully-unrolled static 2-buffer
// software pipeline so bf[j+1] loads issue ~1400 cycles before use.
__global__ __launch_bounds__(256, 2) void k_gemm(
        const unsigned char* __restrict__ EF,
        const unsigned char* __restrict__ BF,
        const float* __restrict__ badj,
        double* __restrict__ pGemm)
{
    const int tid  = threadIdx.x;
    const int wave = tid >> 6;
    const int lane = tid & 63;
    const int rg   = blockIdx.x >> 4;     // 256-row group (0..63)
    const int cg   = blockIdx.x & 15;     // 256-col group (0..15)
    const int ag0  = rg * 16 + wave * 4;  // A 16-row group base
    const int r16  = lane & 15;

    i32x8 af[2][4];
    #pragma unroll
    for (int s = 0; s < 2; ++s)
        #pragma unroll
        for (int mi = 0; mi < 4; ++mi)
            af[s][mi] = *(const i32x8*)(EF + (size_t)(ag0 + mi) * 4096
                                        + s * 2048 + lane * 32);

#define LOAD_B(bf, ba, j) do {                                              \
        const int bg0_ = cg * 16 + (j) * 4;                                 \
        _Pragma("unroll")                                                   \
        for (int s_ = 0; s_ < 2; ++s_)                                      \
            _Pragma("unroll")                                               \
            for (int ni_ = 0; ni_ < 4; ++ni_)                               \
                bf[s_][ni_] = *(const i32x8*)(BF + (size_t)(bg0_ + ni_) * 4096 \
                                              + s_ * 2048 + lane * 32);     \
        _Pragma("unroll")                                                   \
        for (int ni_ = 0; ni_ < 4; ++ni_)                                   \
            ba[ni_] = badj[cg * 256 + (j) * 64 + ni_ * 16 + r16];           \
    } while (0)

#define COMPUTE_J(bf, ba) do {                                              \
        _Pragma("unroll")                                                   \
        for (int mi_ = 0; mi_ < 4; ++mi_) {                                 \
            f32x4 acc[4] = {};                                              \
            _Pragma("unroll")                                               \
            for (int s_ = 0; s_ < 2; ++s_)                                  \
                _Pragma("unroll")                                           \
                for (int ni_ = 0; ni_ < 4; ++ni_)                           \
                    acc[ni_] = __builtin_amdgcn_mfma_scale_f32_16x16x128_f8f6f4( \
                        af[s_][mi_], bf[s_][ni_], acc[ni_],                 \
                        0, 0,                 /* cbsz=fp8, blgp=fp8 */      \
                        0, 0x7F7F7F7F,        /* scale A = 2^0 */           \
                        0, 0x7B7B7B7B);       /* scale B = 2^-4 */          \
            _Pragma("unroll")                                               \
            for (int ni_ = 0; ni_ < 4; ++ni_)                               \
                softplus4_acc(acc[ni_] + ba[ni_], vsum);                    \
        }                                                                   \
    } while (0)

    i32x8 bfA[2][4], bfB[2][4];
    float baA[4], baB[4];

    LOAD_B(bfA, baA, 0);
    LOAD_B(bfB, baB, 1);

    // Pin af: "+v" redefines the values here, so the allocator cannot
    // re-sink the EF loads into the compute phases (r1: VGPR=84 proved it
    // was doing exactly that). Placed after 48 loads are in flight so the
    // implied wait costs ~nothing.
    #pragma unroll
    for (int s = 0; s < 2; ++s)
        #pragma unroll
        for (int mi = 0; mi < 4; ++mi)
            asm volatile("" : "+v"(af[s][mi]));

    f32x4 vsum = {};

    COMPUTE_J(bfA, baA);      // j=0 (bfA loaded, bfB in flight)
    LOAD_B(bfA, baA, 2);      // prefetch j=2 under j=1's compute
    COMPUTE_J(bfB, baB);      // j=1
    LOAD_B(bfB, baB, 3);      // prefetch j=3 under j=2's compute
    COMPUTE_J(bfA, baA);      // j=2
    COMPUTE_J(bfB, baB);      // j=3

#undef LOAD_B
#undef COMPUTE_J

    float lsum = (vsum.x + vsum.y) + (vsum.z + vsum.w);
    #pragma unroll
    for (int off = 32; off > 0; off >>= 1) lsum += __shfl_down(lsum, off, 64);
    __shared__ float wsum[4];
    if (lane == 0) wsum[wave] = lsum;
    __syncthreads();
    if (tid == 0)
        pGemm[blockIdx.x] = (double)((wsum[0] + wsum[1]) + (wsum[2] + wsum[3]));
}

__global__ __launch_bounds__(256) void k_final(
        const double* __restrict__ pTrue, const double* __restrict__ pGemm,
        float* __restrict__ out)
{
    const int tid = threadIdx.x, wave = tid >> 6, lane = tid & 63;
    double s = 0.0;
    for (int i = tid; i < 1024; i += 256) s += pTrue[i];
    for (int i = tid; i < 1024; i += 256) s += pGemm[i];
    #pragma unroll
    for (int off = 32; off > 0; off >>= 1) s += __shfl_down(s, off, 64);
    __shared__ double wsum[4];
    if (lane == 0) wsum[wave] = s;
    __syncthreads();
    if (tid == 0)
        out[0] = (float)(((wsum[0] + wsum[1]) + (wsum[2] + wsum[3]))
                         * (1.0 / (double)BATCH));
}

// ---------- launch ----------

extern "C" void kernel_launch(void* const* d_in, const int* in_sizes, int n_in,
                              void* d_out, int out_size, void* d_ws, size_t ws_size,
                              hipStream_t stream) {
    const float* emb  = (const float*)d_in[0];
    const int*   tgt  = (const int*)d_in[1];
    const int*   sids = (const int*)d_in[2];
    const float* W    = (const float*)d_in[3];
    const float* bias = (const float*)d_in[4];
    float* out = (float*)d_out;

    char* ws = (char*)d_ws;
    double*        pTrue = (double*)ws;                        // 1024 doubles
    double*        pGemm = (double*)(ws + 8192);               // 1024 doubles
    float*         badj  = (float*)(ws + 40960);               // 16 KB
    unsigned char* BF    = (unsigned char*)(ws + 57344);       // 1 MB
    unsigned char* EF    = (unsigned char*)(ws + 57344 + 1048576); // 4 MB

    hipLaunchKernelGGL(k_prep, dim3(1088), dim3(256), 0, stream,
                       emb, tgt, sids, W, bias, EF, BF, badj, pTrue);
    hipLaunchKernelGGL(k_gemm, dim3(1024), dim3(256), 0, stream,
                       EF, BF, badj, pGemm);
    hipLaunchKernelGGL(k_final, dim3(1), dim3(256), 0, stream,
                       pTrue, pGemm, out);
}

// Round 4
// 130.561 us; speedup vs baseline: 1.0677x; 1.0165x over previous
//
#include <hip/hip_runtime.h>
#include <cstdint>
#include <cstddef>

#define VOCAB 50000
#define EMBED 256
#define BATCH 16384
#define NSAMP 4096

typedef float f32x4 __attribute__((ext_vector_type(4)));
typedef int   i32x8 __attribute__((ext_vector_type(8)));

// ---------- helpers ----------

__device__ __forceinline__ f32x4 vsplat(float a) {
    f32x4 r = {a, a, a, a};
    return r;
}

// Pure-HW log(expected_count): no libm calls (validated r6-r8, absmax 0.0).
__device__ __forceinline__ float log_expected_count(int id) {
    float u = 1.0f / ((float)id + 1.0f);
    float a = __logf(1.0f + u);
    float p = a * 0.09242324f;   // 1/log(50001)
    float ser = p * (1.0f + p * (0.5f + p * (0.33333333f + p * (0.25f + p * 0.2f))));
    float q = -(float)NSAMP * ser;
    return __logf(1.0f - __expf(q));
}

// softplus(x) = max(x,0) + log1p(e^{-|x|}); deg-5 minimax (|err|<=1e-5)
__device__ __forceinline__ float softplus_f(float x) {
    float v = __expf(-fabsf(x));
    float p = fmaf(v, 0.03215845f, -0.13606275f);
    p = fmaf(v, p, 0.28947478f);
    p = fmaf(v, p, -0.49190896f);
    p = fmaf(v, p, 0.99949556f);
    return fmaxf(x, 0.0f) + v * p;
}

// Packed-f32 softplus over 4 elements (v_pk_* on gfx950), 4-wide acc chain.
__device__ __forceinline__ void softplus4_acc(f32x4 x, f32x4& vsum) {
    f32x4 ax = __builtin_elementwise_abs(x);
    f32x4 v;
    v.x = __expf(-ax.x);
    v.y = __expf(-ax.y);
    v.z = __expf(-ax.z);
    v.w = __expf(-ax.w);
    f32x4 p = __builtin_elementwise_fma(v, vsplat(0.03215845f), vsplat(-0.13606275f));
    p = __builtin_elementwise_fma(v, p, vsplat(0.28947478f));
    p = __builtin_elementwise_fma(v, p, vsplat(-0.49190896f));
    p = __builtin_elementwise_fma(v, p, vsplat(0.99949556f));
    vsum += __builtin_elementwise_max(x, vsplat(0.0f));
    vsum = __builtin_elementwise_fma(v, p, vsum);
}

// pack 4 floats -> 4 fp8 e4m3 bytes (HW cvt, OCP on gfx950)
__device__ __forceinline__ int pk4_fp8(float a, float b, float c, float d) {
    int v = __builtin_amdgcn_cvt_pk_fp8_f32(a, b, 0, false);
    v = __builtin_amdgcn_cvt_pk_fp8_f32(c, d, v, true);
    return v;
}

// Fragment-order layout for an R x 256 fp8 matrix:
//   offset(r,k) = (r>>4)*4096 + (k>>5)*512 + (r&15)*32 + (k&31)
// Wave frag (group g, k-step s): contiguous 2KB at g*4096 + s*2048,
// per-lane 32B at +lane*32 (lane&15 = row, lane>>4 = k-quad).

// ---------- kernels ----------

// blocks [0,1024): true logits + E -> fp8 fragments (1 wave = 4 rows)
// blocks [1024,1088): gather W[sids] * 16 -> fp8 fragments + badj
__global__ __launch_bounds__(256) void k_prep(
        const float* __restrict__ E, const int* __restrict__ tgt,
        const int* __restrict__ sids, const float* __restrict__ W,
        const float* __restrict__ bias,
        unsigned char* __restrict__ EF, unsigned char* __restrict__ BF,
        float* __restrict__ badj, double* __restrict__ pTrue)
{
    const int blk = blockIdx.x, tid = threadIdx.x;
    const int wave = tid >> 6, lane = tid & 63;

    if (blk < 1024) {
        float tsum = 0.0f;
        #pragma unroll
        for (int i = 0; i < 4; ++i) {
            int b = (blk * 4 + wave) + 4096 * i;
            int label = tgt[b];
            float4 e  = ((const float4*)(E + (size_t)b * EMBED))[lane];
            float4 wv = ((const float4*)(W + (size_t)label * EMBED))[lane];
            int pk = pk4_fp8(e.x, e.y, e.z, e.w);
            *(int*)(EF + ((b >> 4) * 4096 + (lane >> 3) * 512
                          + (b & 15) * 32 + (lane & 7) * 4)) = pk;
            float d = e.x * wv.x + e.y * wv.y + e.z * wv.z + e.w * wv.w;
            #pragma unroll
            for (int off = 32; off > 0; off >>= 1) d += __shfl_down(d, off, 64);
            if (lane == 0) {
                float tl = d + bias[label] - log_expected_count(label);
                tsum += softplus_f(-tl);
            }
        }
        __shared__ float ts[4];
        if (lane == 0) ts[wave] = tsum;
        __syncthreads();
        if (tid == 0) pTrue[blk] = (double)((ts[0] + ts[1]) + (ts[2] + ts[3]));
    } else {
        #pragma unroll
        for (int i = 0; i < 4; ++i) {
            int task = (blk - 1024) * 256 + tid + 16384 * i;
            int s = task >> 4, p = task & 15;   // p = 16B chunk, k = p*16
            int sid = sids[s];
            const float4* wr = (const float4*)(W + (size_t)sid * EMBED + p * 16);
            float4 w0 = wr[0], w1 = wr[1], w2 = wr[2], w3 = wr[3];
            int4 o;
            o.x = pk4_fp8(w0.x * 16.0f, w0.y * 16.0f, w0.z * 16.0f, w0.w * 16.0f);
            o.y = pk4_fp8(w1.x * 16.0f, w1.y * 16.0f, w1.z * 16.0f, w1.w * 16.0f);
            o.z = pk4_fp8(w2.x * 16.0f, w2.y * 16.0f, w2.z * 16.0f, w2.w * 16.0f);
            o.w = pk4_fp8(w3.x * 16.0f, w3.y * 16.0f, w3.z * 16.0f, w3.w * 16.0f);
            *(int4*)(BF + ((s >> 4) * 4096 + (p >> 1) * 512
                           + (s & 15) * 32 + (p & 1) * 16)) = o;
            if (p == 0) badj[s] = bias[sid] - log_expected_count(sid);
        }
    }
}

// GEMM: MX-fp8, A in registers, B staged in LDS once per block.
// r1/r2 history: demand-loading B per wave (4 waves x 1024 blocks x 64KB =
// 256MB redundant L2 traffic, 32/48 per-wave VMEM bursts) left the kernel
// operand-latency-bound at ~38us (MfmaUtil 13.5, VALUBusy 30 at r1).
// Now: cooperative global_load_lds (width=16) stages the 64KB B panel once,
// per-j fragments come from ds_read_b128 (~120cy, hidden under ~1500cy
// compute). 64KB x 2 blocks/CU = 128KB <= 160KB, occupancy unchanged.
// No LDS swizzle yet: lane*32 reads are ~4-way/quarter-wave (~1.58x on a
// non-critical ~800cy LDS path) — add 16B-granule XOR swizzle only if
// SQ_LDS_BANK_CONFLICT shows it matters.
__global__ __launch_bounds__(256, 2) void k_gemm(
        const unsigned char* __restrict__ EF,
        const unsigned char* __restrict__ BF,
        const float* __restrict__ badj,
        double* __restrict__ pGemm)
{
    const int tid  = threadIdx.x;
    const int wave = tid >> 6;
    const int lane = tid & 63;
    const int rg   = blockIdx.x >> 4;     // 256-row group (0..63)
    const int cg   = blockIdx.x & 15;     // 256-col group (0..15)
    const int ag0  = rg * 16 + wave * 4;  // A 16-row group base
    const int r16  = lane & 15;

    __shared__ unsigned char Blds[65536];

    // Issue private A loads first (16 x 32B per lane)...
    i32x8 af[2][4];
    #pragma unroll
    for (int s = 0; s < 2; ++s)
        #pragma unroll
        for (int mi = 0; mi < 4; ++mi)
            af[s][mi] = *(const i32x8*)(EF + (size_t)(ag0 + mi) * 4096
                                        + s * 2048 + lane * 32);

    // ...then cooperatively stage the 64KB B panel (linear copy; BF is
    // already in fragment order). LDS dest = wave-uniform base + lane*16
    // (HW rule); global source is per-lane.
    {
        const unsigned char* Bsrc = BF + (size_t)cg * 65536;
        #pragma unroll
        for (int it = 0; it < 16; ++it) {
            int woff = it * 4096 + wave * 1024;       // wave-uniform LDS base
            int goff = woff + lane * 16;              // this lane's source
            __builtin_amdgcn_global_load_lds(
                (const __attribute__((address_space(1))) void*)(Bsrc + goff),
                (__attribute__((address_space(3))) void*)(Blds + woff),
                16, 0, 0);
        }
    }

    asm volatile("s_waitcnt vmcnt(0)");
    __syncthreads();

    // Pin af in registers: the allocator must not re-sink EF loads into the
    // compute phases (r1: VGPR_Count=84 proved it did exactly that).
    #pragma unroll
    for (int s = 0; s < 2; ++s)
        #pragma unroll
        for (int mi = 0; mi < 4; ++mi)
            asm volatile("" : "+v"(af[s][mi]));

    f32x4 vsum = {};

    #pragma unroll 1
    for (int j = 0; j < 4; ++j) {
        i32x8 bf[2][4];
        #pragma unroll
        for (int s = 0; s < 2; ++s)
            #pragma unroll
            for (int ni = 0; ni < 4; ++ni)
                bf[s][ni] = *(const i32x8*)(Blds + (j * 4 + ni) * 4096
                                            + s * 2048 + lane * 32);

        float ba[4];
        #pragma unroll
        for (int ni = 0; ni < 4; ++ni)
            ba[ni] = badj[cg * 256 + j * 64 + ni * 16 + r16];

        #pragma unroll
        for (int mi = 0; mi < 4; ++mi) {
            f32x4 acc[4] = {};
            #pragma unroll
            for (int s = 0; s < 2; ++s)
                #pragma unroll
                for (int ni = 0; ni < 4; ++ni)
                    acc[ni] = __builtin_amdgcn_mfma_scale_f32_16x16x128_f8f6f4(
                        af[s][mi], bf[s][ni], acc[ni],
                        0, 0,                 // cbsz=fp8, blgp=fp8
                        0, 0x7F7F7F7F,        // scale A = 2^0
                        0, 0x7B7B7B7B);       // scale B = 2^-4 (undo W*16)
            #pragma unroll
            for (int ni = 0; ni < 4; ++ni)
                softplus4_acc(acc[ni] + ba[ni], vsum);
        }
    }

    float lsum = (vsum.x + vsum.y) + (vsum.z + vsum.w);
    #pragma unroll
    for (int off = 32; off > 0; off >>= 1) lsum += __shfl_down(lsum, off, 64);
    __shared__ float wsum[4];
    if (lane == 0) wsum[wave] = lsum;
    __syncthreads();
    if (tid == 0)
        pGemm[blockIdx.x] = (double)((wsum[0] + wsum[1]) + (wsum[2] + wsum[3]));
}

__global__ __launch_bounds__(256) void k_final(
        const double* __restrict__ pTrue, const double* __restrict__ pGemm,
        float* __restrict__ out)
{
    const int tid = threadIdx.x, wave = tid >> 6, lane = tid & 63;
    double s = 0.0;
    for (int i = tid; i < 1024; i += 256) s += pTrue[i];
    for (int i = tid; i < 1024; i += 256) s += pGemm[i];
    #pragma unroll
    for (int off = 32; off > 0; off >>= 1) s += __shfl_down(s, off, 64);
    __shared__ double wsum[4];
    if (lane == 0) wsum[wave] = s;
    __syncthreads();
    if (tid == 0)
        out[0] = (float)(((wsum[0] + wsum[1]) + (wsum[2] + wsum[3]))
                         * (1.0 / (double)BATCH));
}

// ---------- launch ----------

extern "C" void kernel_launch(void* const* d_in, const int* in_sizes, int n_in,
                              void* d_out, int out_size, void* d_ws, size_t ws_size,
                              hipStream_t stream) {
    const float* emb  = (const float*)d_in[0];
    const int*   tgt  = (const int*)d_in[1];
    const int*   sids = (const int*)d_in[2];
    const float* W    = (const float*)d_in[3];
    const float* bias = (const float*)d_in[4];
    float* out = (float*)d_out;

    char* ws = (char*)d_ws;
    double*        pTrue = (double*)ws;                        // 1024 doubles
    double*        pGemm = (double*)(ws + 8192);               // 1024 doubles
    float*         badj  = (float*)(ws + 40960);               // 16 KB
    unsigned char* BF    = (unsigned char*)(ws + 57344);       // 1 MB
    unsigned char* EF    = (unsigned char*)(ws + 57344 + 1048576); // 4 MB

    hipLaunchKernelGGL(k_prep, dim3(1088), dim3(256), 0, stream,
                       emb, tgt, sids, W, bias, EF, BF, badj, pTrue);
    hipLaunchKernelGGL(k_gemm, dim3(1024), dim3(256), 0, stream,
                       EF, BF, badj, pGemm);
    hipLaunchKernelGGL(k_final, dim3(1), dim3(256), 0, stream,
                       pTrue, pGemm, out);
}

// Round 11
// 129.011 us; speedup vs baseline: 1.0806x; 1.0120x over previous
//
#include <hip/hip_runtime.h>
#include <cstdint>
#include <cstddef>

#define VOCAB 50000
#define EMBED 256
#define BATCH 16384
#define NSAMP 4096

typedef float f32x4 __attribute__((ext_vector_type(4)));
typedef int   i32x4 __attribute__((ext_vector_type(4)));
typedef int   i32x8 __attribute__((ext_vector_type(8)));

// ---------- helpers ----------

__device__ __forceinline__ f32x4 vsplat(float a) {
    f32x4 r = {a, a, a, a};
    return r;
}

// Pure-HW log(expected_count): no libm calls (validated r6-r8, absmax 0.0).
__device__ __forceinline__ float log_expected_count(int id) {
    float u = 1.0f / ((float)id + 1.0f);
    float a = __logf(1.0f + u);
    float p = a * 0.09242324f;   // 1/log(50001)
    float ser = p * (1.0f + p * (0.5f + p * (0.33333333f + p * (0.25f + p * 0.2f))));
    float q = -(float)NSAMP * ser;
    return __logf(1.0f - __expf(q));
}

// softplus(x) = max(x,0) + log1p(e^{-|x|}); deg-5 minimax (|err|<=1e-5)
__device__ __forceinline__ float softplus_f(float x) {
    float v = __expf(-fabsf(x));
    float p = fmaf(v, 0.03215845f, -0.13606275f);
    p = fmaf(v, p, 0.28947478f);
    p = fmaf(v, p, -0.49190896f);
    p = fmaf(v, p, 0.99949556f);
    return fmaxf(x, 0.0f) + v * p;
}

// Packed-f32 softplus over 4 elements (v_pk_* on gfx950), 4-wide acc chain.
__device__ __forceinline__ void softplus4_acc(f32x4 x, f32x4& vsum) {
    f32x4 ax = __builtin_elementwise_abs(x);
    f32x4 v;
    v.x = __expf(-ax.x);
    v.y = __expf(-ax.y);
    v.z = __expf(-ax.z);
    v.w = __expf(-ax.w);
    f32x4 p = __builtin_elementwise_fma(v, vsplat(0.03215845f), vsplat(-0.13606275f));
    p = __builtin_elementwise_fma(v, p, vsplat(0.28947478f));
    p = __builtin_elementwise_fma(v, p, vsplat(-0.49190896f));
    p = __builtin_elementwise_fma(v, p, vsplat(0.99949556f));
    vsum += __builtin_elementwise_max(x, vsplat(0.0f));
    vsum = __builtin_elementwise_fma(v, p, vsum);
}

// pack 4 floats -> 4 fp8 e4m3 bytes (HW cvt, OCP on gfx950)
__device__ __forceinline__ int pk4_fp8(float a, float b, float c, float d) {
    int v = __builtin_amdgcn_cvt_pk_fp8_f32(a, b, 0, false);
    v = __builtin_amdgcn_cvt_pk_fp8_f32(c, d, v, true);
    return v;
}

// EF (A matrix) layout — unchanged 32B-chunk fragment order:
//   offset(r,k) = (r>>4)*4096 + (k>>5)*512 + (r&15)*32 + (k&31)
// BF (B matrix) layout — NEW 16B-plane split (LDS bank fix): within each
// 512B k-block, the two 16B halves of a row's 32B chunk live in separate
// 256B planes:
//   offset(r,k) = (r>>4)*4096 + (k>>5)*512 + ((k>>4)&1)*256 + (r&15)*16 + (k&15)
// A wave's ds_read_b128 then covers contiguous 256B runs per 16 lanes ->
// all 32 banks hit evenly (8 accesses/bank = theoretical minimum), vs the
// old chunk layout which hit only banks {0-3,8-11,16-19,24-27} (2x penalty).

// ---------- kernels ----------

// blocks [0,1024): true logits + E -> fp8 fragments (1 wave = 4 rows)
// blocks [1024,1088): gather W[sids] * 16 -> fp8 fragments + badj
__global__ __launch_bounds__(256) void k_prep(
        const float* __restrict__ E, const int* __restrict__ tgt,
        const int* __restrict__ sids, const float* __restrict__ W,
        const float* __restrict__ bias,
        unsigned char* __restrict__ EF, unsigned char* __restrict__ BF,
        float* __restrict__ badj, double* __restrict__ pTrue)
{
    const int blk = blockIdx.x, tid = threadIdx.x;
    const int wave = tid >> 6, lane = tid & 63;

    if (blk < 1024) {
        float tsum = 0.0f;
        #pragma unroll
        for (int i = 0; i < 4; ++i) {
            int b = (blk * 4 + wave) + 4096 * i;
            int label = tgt[b];
            float4 e  = ((const float4*)(E + (size_t)b * EMBED))[lane];
            float4 wv = ((const float4*)(W + (size_t)label * EMBED))[lane];
            int pk = pk4_fp8(e.x, e.y, e.z, e.w);
            *(int*)(EF + ((b >> 4) * 4096 + (lane >> 3) * 512
                          + (b & 15) * 32 + (lane & 7) * 4)) = pk;
            float d = e.x * wv.x + e.y * wv.y + e.z * wv.z + e.w * wv.w;
            #pragma unroll
            for (int off = 32; off > 0; off >>= 1) d += __shfl_down(d, off, 64);
            if (lane == 0) {
                float tl = d + bias[label] - log_expected_count(label);
                tsum += softplus_f(-tl);
            }
        }
        __shared__ float ts[4];
        if (lane == 0) ts[wave] = tsum;
        __syncthreads();
        if (tid == 0) pTrue[blk] = (double)((ts[0] + ts[1]) + (ts[2] + ts[3]));
    } else {
        #pragma unroll
        for (int i = 0; i < 4; ++i) {
            int task = (blk - 1024) * 256 + tid + 16384 * i;
            int s = task >> 4, p = task & 15;   // p = 16B chunk, k = p*16
            int sid = sids[s];
            const float4* wr = (const float4*)(W + (size_t)sid * EMBED + p * 16);
            float4 w0 = wr[0], w1 = wr[1], w2 = wr[2], w3 = wr[3];
            int4 o;
            o.x = pk4_fp8(w0.x * 16.0f, w0.y * 16.0f, w0.z * 16.0f, w0.w * 16.0f);
            o.y = pk4_fp8(w1.x * 16.0f, w1.y * 16.0f, w1.z * 16.0f, w1.w * 16.0f);
            o.z = pk4_fp8(w2.x * 16.0f, w2.y * 16.0f, w2.z * 16.0f, w2.w * 16.0f);
            o.w = pk4_fp8(w3.x * 16.0f, w3.y * 16.0f, w3.z * 16.0f, w3.w * 16.0f);
            // plane-split store: q = p>>1, h = p&1
            *(int4*)(BF + ((s >> 4) * 4096 + (p >> 1) * 512 + (p & 1) * 256
                           + (s & 15) * 16)) = o;
            if (p == 0) badj[s] = bias[sid] - log_expected_count(sid);
        }
    }
}

// GEMM: MX-fp8, A in registers, B staged in LDS once per block.
// r6 restructure: 512-thread blocks (8 waves x 32 rows). The r4 af-resident
// design (64 VGPR) forced (256,2) = 2 waves/SIMD -> latency-bound (r1:
// Mfma 13.5 / VALU 30 / Occ 20). Halving the per-wave A tile fits a
// (512,4) = 128-VGPR budget -> 4 waves/SIMD at the same LDS (64KB, 2
// blocks/CU). B reads use the 16B-plane layout -> bank-conflict-free.
__global__ __launch_bounds__(512, 4) void k_gemm(
        const unsigned char* __restrict__ EF,
        const unsigned char* __restrict__ BF,
        const float* __restrict__ badj,
        double* __restrict__ pGemm)
{
    const int tid  = threadIdx.x;
    const int wave = tid >> 6;            // 0..7
    const int lane = tid & 63;
    const int rg   = blockIdx.x >> 4;     // 256-row group (0..63)
    const int cg   = blockIdx.x & 15;     // 256-col group (0..15)
    const int ag0  = rg * 16 + wave * 2;  // A 16-row group base (2 groups/wave)
    const int r16  = lane & 15;

    __shared__ unsigned char Blds[65536];
    __shared__ float wsum[8];

    // A fragments: 2 k-steps x 2 row-groups = 4 x 32B per lane (EF layout
    // unchanged; A never goes through LDS).
    i32x8 af[2][2];
    #pragma unroll
    for (int s = 0; s < 2; ++s)
        #pragma unroll
        for (int mi = 0; mi < 2; ++mi)
            af[s][mi] = *(const i32x8*)(EF + (size_t)(ag0 + mi) * 4096
                                        + s * 2048 + lane * 32);

    // Cooperative stage of the 64KB B panel (linear byte copy, layout-agnostic).
    {
        const unsigned char* Bsrc = BF + (size_t)cg * 65536;
        #pragma unroll
        for (int it = 0; it < 8; ++it) {
            int woff = it * 8192 + wave * 1024;   // wave-uniform LDS base
            int goff = woff + lane * 16;
            __builtin_amdgcn_global_load_lds(
                (const __attribute__((address_space(1))) void*)(Bsrc + goff),
                (__attribute__((address_space(3))) void*)(Blds + woff),
                16, 0, 0);
        }
    }

    asm volatile("s_waitcnt vmcnt(0)");
    __syncthreads();

    // Pin af in registers (r1 lesson: allocator re-sinks global loads into
    // the loop if not pinned).
    #pragma unroll
    for (int s = 0; s < 2; ++s)
        #pragma unroll
        for (int mi = 0; mi < 2; ++mi)
            asm volatile("" : "+v"(af[s][mi]));

    f32x4 vsum = {};
    const int lbase = (lane >> 4) * 512 + r16 * 16;  // per-lane base in 4KB group

    #pragma unroll 1
    for (int j = 0; j < 4; ++j) {
        float ba[4];
        #pragma unroll
        for (int ni = 0; ni < 4; ++ni)
            ba[ni] = badj[cg * 256 + j * 64 + ni * 16 + r16];

        f32x4 acc[2][4] = {};
        #pragma unroll
        for (int s = 0; s < 2; ++s) {
            i32x8 bf[4];
            #pragma unroll
            for (int ni = 0; ni < 4; ++ni) {
                const unsigned char* bp = Blds + (j * 4 + ni) * 4096
                                          + s * 2048 + lbase;
                i32x4 lo = *(const i32x4*)bp;          // k 0..15 of lane's 32
                i32x4 hi = *(const i32x4*)(bp + 256);  // k 16..31
                bf[ni][0] = lo[0]; bf[ni][1] = lo[1];
                bf[ni][2] = lo[2]; bf[ni][3] = lo[3];
                bf[ni][4] = hi[0]; bf[ni][5] = hi[1];
                bf[ni][6] = hi[2]; bf[ni][7] = hi[3];
            }
            #pragma unroll
            for (int mi = 0; mi < 2; ++mi)
                #pragma unroll
                for (int ni = 0; ni < 4; ++ni)
                    acc[mi][ni] = __builtin_amdgcn_mfma_scale_f32_16x16x128_f8f6f4(
                        af[s][mi], bf[ni], acc[mi][ni],
                        0, 0,                 // cbsz=fp8, blgp=fp8
                        0, 0x7F7F7F7F,        // scale A = 2^0
                        0, 0x7B7B7B7B);       // scale B = 2^-4 (undo W*16)
        }

        #pragma unroll
        for (int mi = 0; mi < 2; ++mi)
            #pragma unroll
            for (int ni = 0; ni < 4; ++ni)
                softplus4_acc(acc[mi][ni] + ba[ni], vsum);
    }

    float lsum = (vsum.x + vsum.y) + (vsum.z + vsum.w);
    #pragma unroll
    for (int off = 32; off > 0; off >>= 1) lsum += __shfl_down(lsum, off, 64);
    if (lane == 0) wsum[wave] = lsum;
    __syncthreads();
    if (tid == 0)
        pGemm[blockIdx.x] = (double)((((wsum[0] + wsum[1]) + (wsum[2] + wsum[3]))
                                    + ((wsum[4] + wsum[5]) + (wsum[6] + wsum[7]))));
}

__global__ __launch_bounds__(256) void k_final(
        const double* __restrict__ pTrue, const double* __restrict__ pGemm,
        float* __restrict__ out)
{
    const int tid = threadIdx.x, wave = tid >> 6, lane = tid & 63;
    double s = 0.0;
    for (int i = tid; i < 1024; i += 256) s += pTrue[i];
    for (int i = tid; i < 1024; i += 256) s += pGemm[i];
    #pragma unroll
    for (int off = 32; off > 0; off >>= 1) s += __shfl_down(s, off, 64);
    __shared__ double wsum[4];
    if (lane == 0) wsum[wave] = s;
    __syncthreads();
    if (tid == 0)
        out[0] = (float)(((wsum[0] + wsum[1]) + (wsum[2] + wsum[3]))
                         * (1.0 / (double)BATCH));
}

// ---------- launch ----------

extern "C" void kernel_launch(void* const* d_in, const int* in_sizes, int n_in,
                              void* d_out, int out_size, void* d_ws, size_t ws_size,
                              hipStream_t stream) {
    const float* emb  = (const float*)d_in[0];
    const int*   tgt  = (const int*)d_in[1];
    const int*   sids = (const int*)d_in[2];
    const float* W    = (const float*)d_in[3];
    const float* bias = (const float*)d_in[4];
    float* out = (float*)d_out;

    char* ws = (char*)d_ws;
    double*        pTrue = (double*)ws;                        // 1024 doubles
    double*        pGemm = (double*)(ws + 8192);               // 1024 doubles
    float*         badj  = (float*)(ws + 40960);               // 16 KB
    unsigned char* BF    = (unsigned char*)(ws + 57344);       // 1 MB
    unsigned char* EF    = (unsigned char*)(ws + 57344 + 1048576); // 4 MB

    hipLaunchKernelGGL(k_prep, dim3(1088), dim3(256), 0, stream,
                       emb, tgt, sids, W, bias, EF, BF, badj, pTrue);
    hipLaunchKernelGGL(k_gemm, dim3(1024), dim3(512), 0, stream,
                       EF, BF, badj, pGemm);
    hipLaunchKernelGGL(k_final, dim3(1), dim3(256), 0, stream,
                       pTrue, pGemm, out);
}